// Round 8
// baseline (374.850 us; speedup 1.0000x reference)
//
#include <hip/hip_runtime.h>
#include <math.h>

#ifndef M_PI
#define M_PI 3.14159265358979323846
#endif

constexpr int S_LEN    = 176400;
constexpr int NFFT     = 2048;
constexpr int NC       = 1024;
constexpr int HOP_     = 441;
constexpr int T_FRAMES = 401;
constexpr int F_BINS   = 1025;
constexpr int F_STRIDE = 1028;     // fp32 spec row stride (16B aligned)
constexpr int N_CH     = 64;
constexpr float EPS_   = 1e-8f;
constexpr float C1_    = 0.0004f;
constexpr float C2_    = 0.0036f;
constexpr float COV_NORM_ = 49.0f / 48.0f;

// workspace float offsets
constexpr int WIN_OFF  = 0;        // float[2048] hann window
constexpr int TWG_OFF  = 2048;     // float2[768]  tw[e] = exp(-2pi i e/1024)
constexpr int UTW_OFF  = 3584;     // float2[1025] exp(-i pi r/1024)
constexpr int SPEC_OFF = 5696;

// ssim wave decomposition: 5 column bands x 33 row chunks per channel.
// R7 counters: occupancy 26%, VALU 47% at 1360 blocks -> starved of waves.
// ROWS_PW 24->12 doubles the grid (2640 blocks ~ 10.3/CU -> residency caps at
// the 6-block VGPR limit).
constexpr int ROWS_PW   = 12;
constexpr int NCHUNKS_R = 33;      // ceil(395/12)
constexpr int BANDS     = 5;
constexpr int BAND_ADV  = 248;     // 62 producing lanes * 4 cols

// native 2xf32 vector type -> VGPR pair, usable as inline-asm operand
typedef float vf2 __attribute__((ext_vector_type(2)));

// LDS bank swizzle: phys(i) = i ^ ((i>>2)&15) ^ ((i>>6)&15) (bijective,
// conflict-checked per access pattern in R2).
__device__ __forceinline__ int phys(int i) { return i ^ ((i >> 2) & 15) ^ ((i >> 6) & 15); }

// ---- packed-f32 complex primitives (VOP3P), absmax-verified in R7.
__device__ __forceinline__ vf2 pk_add(vf2 a, vf2 b) {
    vf2 r; asm("v_pk_add_f32 %0, %1, %2" : "=v"(r) : "v"(a), "v"(b)); return r;
}
__device__ __forceinline__ vf2 pk_sub(vf2 a, vf2 b) {
    vf2 r; asm("v_pk_add_f32 %0, %1, %2 neg_lo:[0,1] neg_hi:[0,1]" : "=v"(r) : "v"(a), "v"(b)); return r;
}
// {b.x + d.y, b.y - d.x}  == b - i*d
__device__ __forceinline__ vf2 pk_sub_i(vf2 b, vf2 d) {
    vf2 r; asm("v_pk_add_f32 %0, %1, %2 op_sel:[0,1] op_sel_hi:[1,0] neg_hi:[0,1]"
               : "=v"(r) : "v"(b), "v"(d)); return r;
}
// {b.x - d.y, b.y + d.x}  == b + i*d
__device__ __forceinline__ vf2 pk_add_i(vf2 b, vf2 d) {
    vf2 r; asm("v_pk_add_f32 %0, %1, %2 op_sel:[0,1] op_sel_hi:[1,0] neg_lo:[0,1]"
               : "=v"(r) : "v"(b), "v"(d)); return r;
}
// complex multiply y*w
__device__ __forceinline__ vf2 pk_cmul(vf2 y, vf2 w) {
    vf2 t, r;
    asm("v_pk_mul_f32 %0, %1, %2 op_sel:[0,0] op_sel_hi:[0,1]"
        : "=v"(t) : "v"(y), "v"(w));
    asm("v_pk_fma_f32 %0, %1, %2, %3 op_sel:[1,1,0] op_sel_hi:[1,0,1] neg_lo:[1,0,0]"
        : "=v"(r) : "v"(y), "v"(w), "v"(t));
    return r;
}

__global__ __launch_bounds__(256) void init_tables_kernel(float* __restrict__ ws, float* __restrict__ out) {
    const int idx = blockIdx.x * 256 + threadIdx.x;
    if (idx < 64) out[idx] = 0.0f;
    if (idx < NFFT) {
        ws[WIN_OFF + idx] = 0.5f - 0.5f * cosf((float)(2.0 * M_PI / NFFT) * (float)idx);
    }
    if (idx < 768) {
        float ang = -2.0f * (float)M_PI * (float)idx / (float)NC;
        float s, c; sincosf(ang, &s, &c);
        ws[TWG_OFF + 2*idx] = c; ws[TWG_OFF + 2*idx+1] = s;
    }
    if (idx < F_BINS) {
        float ang = -(float)M_PI * (float)idx / (float)NC;
        float s, c; sincosf(ang, &s, &c);
        ws[UTW_OFF + 2*idx] = c; ws[UTW_OFF + 2*idx+1] = s;
    }
}

// In-place radix-4 DIF butterfly, packed-f32 (semantics identical to R2-R5)
__device__ __forceinline__ void r4_dif_inplace(
    vf2* __restrict__ A, int r0, int r1, int r2, int r3,
    vf2 w1, vf2 w2, vf2 w3, bool tw)
{
    vf2 x0c = A[r0];
    vf2 x1c = A[r1];
    vf2 x2c = A[r2];
    vf2 x3c = A[r3];

    vf2 a = pk_add(x0c, x2c);
    vf2 b = pk_sub(x0c, x2c);
    vf2 c = pk_add(x1c, x3c);
    vf2 d = pk_sub(x1c, x3c);

    vf2 y0 = pk_add(a, c);
    vf2 y2 = pk_sub(a, c);
    vf2 y1 = pk_sub_i(b, d);
    vf2 y3 = pk_add_i(b, d);

    A[r0] = y0;
    A[r1] = tw ? pk_cmul(y1, w1) : y1;
    A[r2] = tw ? pk_cmul(y2, w2) : y2;
    A[r3] = tw ? pk_cmul(y3, w3) : y3;
}

// Dual 1024-pt in-place radix-4 DIF; one block = frame t of channel ch, both
// tensors.  16 KB LDS -> 8 blocks/CU.  R8: single 64-ch dispatch with the
// R2-R5 XCD channel swizzle RESTORED (R7's split dropped it; input-window L2
// reuse was worth ~20%: FETCH 44 MB vs 420 MB logical).
__global__ __launch_bounds__(256, 8) void stft_mag_kernel(
    const float* __restrict__ x0, const float* __restrict__ x1,
    float* __restrict__ ws, int ch0, int chbase, int nlay, int swizzle)
{
    __shared__ vf2 buf[2 * NC];   // FFT0 at [0,NC), FFT1 at [NC,2NC)

    const int tid = threadIdx.x;

    int ch, t;
    if (swizzle) {
        int g = blockIdx.x;
        ch = ch0 + (g & 7) * 8 + ((g >> 3) & 7);
        t  = g >> 6;
    } else {
        t  = blockIdx.x;
        ch = ch0 + blockIdx.y;
    }

    const float* __restrict__ xin0 = x0 + (size_t)ch * S_LEN;
    const float* __restrict__ xin1 = x1 + (size_t)ch * S_LEN;
    const float* __restrict__ win  = ws + WIN_OFF;
    const vf2*   __restrict__ twg  = (const vf2*)(ws + TWG_OFF);
    const vf2*   __restrict__ utw  = (const vf2*)(ws + UTW_OFF);

    // ---- pack: flat float index n over [0,2048); complex ci = n>>1 (swizzled)
    const int base = t * HOP_ - NFFT / 2;
    float* fA0 = (float*)buf;             // FFT0
    float* fA1 = (float*)(buf + NC);      // FFT1 (+8 KB)
    if (base >= 0 && base + NFFT <= S_LEN) {
        #pragma unroll
        for (int k = 0; k < NFFT / 256; ++k) {
            int n = k * 256 + tid;
            int j = base + n;
            float w = win[n];
            int p = 2 * phys(n >> 1) + (n & 1);
            fA0[p] = xin0[j] * w;
            fA1[p] = xin1[j] * w;
        }
    } else {
        #pragma unroll
        for (int k = 0; k < NFFT / 256; ++k) {
            int n = k * 256 + tid;
            int j = base + n;
            j = (j < 0) ? -j : j;
            j = (j >= S_LEN) ? (2 * S_LEN - 2 - j) : j;
            float w = win[n];
            int p = 2 * phys(n >> 1) + (n & 1);
            fA0[p] = xin0[j] * w;
            fA1[p] = xin1[j] * w;
        }
    }
    __syncthreads();

    // ---- 5-stage in-place radix-4 DIF, x2 FFTs
    #pragma unroll
    for (int s = 0; s < 5; ++s) {
        const int M  = 256 >> (2 * s);
        const int q  = tid & (M - 1);
        const int e  = q << (2 * s);
        const int i0 = 4 * (tid - q) + q;

        const int r0 = phys(i0);
        const int r1 = phys(i0 + M);
        const int r2 = phys(i0 + 2 * M);
        const int r3 = phys(i0 + 3 * M);

        vf2 w1, w2, w3;
        if (s < 4) {
            w1 = twg[e];
            w2 = twg[2 * e];
            w3 = twg[3 * e];
        } else {
            w1.x = 1.0f; w1.y = 0.0f; w2 = w1; w3 = w1;
        }

        r4_dif_inplace(buf,      r0, r1, r2, r3, w1, w2, w3, s < 4);
        r4_dif_inplace(buf + NC, r0, r1, r2, r3, w1, w2, w3, s < 4);

        __syncthreads();
    }

    // ---- real-FFT unpack + magnitude + fp32 coalesced stores (both tensors)
    const size_t perT = (size_t)T_FRAMES * F_STRIDE;
    float* __restrict__ sout0 =
        ws + SPEC_OFF + (size_t)(ch - chbase) * perT + (size_t)t * F_STRIDE;
    float* __restrict__ sout1 = sout0 + (size_t)nlay * perT;

    const int R8 = ((tid & 3) << 6) | ((tid & 12) << 2) | ((tid >> 2) & 12) | ((tid >> 6) & 3);

    #pragma unroll
    for (int k = 0; k < 5; ++k) {
        int r = k * 256 + tid;
        if (k < 4 || tid == 0) {
            const int ra = (k < 4) ? ((R8 << 2) | k) : 0;          // rev4(r & 1023)
            const int rn = (NC - r) & (NC - 1);
            const int rb = ((rn & 3) << 8) | ((rn & 12) << 4) | (rn & 48)
                         | ((rn >> 4) & 12) | ((rn >> 8) & 3);     // rev4(rn)
            const int ia = phys(ra);
            const int ib = phys(rb);
            vf2 wu = utw[r];

            {   // tensor 0
                vf2 Zr = buf[ia];
                vf2 Zn = buf[ib];
                float Ex = 0.5f * (Zr.x + Zn.x);
                float Ey = 0.5f * (Zr.y - Zn.y);
                float Ox = 0.5f * (Zr.y + Zn.y);
                float Oy = 0.5f * (Zn.x - Zr.x);
                float Xx = Ex + wu.x * Ox - wu.y * Oy;
                float Xy = Ey + wu.x * Oy + wu.y * Ox;
                sout0[r] = sqrtf(fmaxf(Xx * Xx + Xy * Xy, EPS_));
            }
            {   // tensor 1
                vf2 Zr = buf[NC + ia];
                vf2 Zn = buf[NC + ib];
                float Ex = 0.5f * (Zr.x + Zn.x);
                float Ey = 0.5f * (Zr.y - Zn.y);
                float Ox = 0.5f * (Zr.y + Zn.y);
                float Oy = 0.5f * (Zn.x - Zr.x);
                float Xx = Ex + wu.x * Ox - wu.y * Oy;
                float Xy = Ey + wu.x * Oy + wu.y * Ox;
                sout1[r] = sqrtf(fmaxf(Xx * Xx + Xy * Xy, EPS_));
            }
        }
    }
}

// SSIM v4: R5 structure (6-row register ring, lane prefixes + __shfl_down,
// 1-ahead prefetch) with (a) ROWS_PW 12 for 2x grid/occupancy, (b) fast-rcp
// division (one v_rcp_f32 per output instead of a full IEEE divide).
#define HWIN7(sarr, W) {                                                     \
    float p0 = sarr[0], p01 = p0 + sarr[1], p012 = p01 + sarr[2],            \
          P = p012 + sarr[3];                                                \
    float a1 = __shfl_down(p012, 1, 64);                                     \
    float A1 = __shfl_down(P,    1, 64);                                     \
    float b0 = __shfl_down(p0,   2, 64);                                     \
    float b1 = __shfl_down(p01,  2, 64);                                     \
    W[0] = P + a1;                                                           \
    W[1] = P - p0 + A1;                                                      \
    W[2] = W[1] - sarr[1] + b0;                                              \
    W[3] = W[2] - sarr[2] + (b1 - b0);                                       \
}

__global__ __launch_bounds__(256) void ssim_kernel(
    const float* __restrict__ ws, float* __restrict__ out,
    int ch0, int nch)
{
    const int tid  = threadIdx.x;
    const int wid  = blockIdx.x * 4 + (tid >> 6);
    const int lane = tid & 63;
    const int total = nch * BANDS * NCHUNKS_R;
    if (wid >= total) return;

    const int cg    = wid / (BANDS * NCHUNKS_R);
    const int rem   = wid - cg * (BANDS * NCHUNKS_R);
    const int band  = rem / NCHUNKS_R;
    const int chunk = rem - band * NCHUNKS_R;

    const int t0 = 3 + chunk * ROWS_PW;
    const int t1 = min(t0 + ROWS_PW, T_FRAMES - 3);   // <= 398

    const int cb = band * BAND_ADV;
    int c4 = cb + 4 * lane;
    if (c4 > 1024) c4 = 1024;      // stay inside the 1028-float row (no OOB)

    const size_t perT = (size_t)T_FRAMES * F_STRIDE;
    const float* __restrict__ X = ws + SPEC_OFF + (size_t)cg * perT + c4;
    const float* __restrict__ Y = ws + SPEC_OFF + ((size_t)nch + cg) * perT + c4;

    const int  fo      = cb + 3 + 4 * lane;   // first output col of this lane
    const bool lane_ok = (lane <= 61);
    const float inv49  = 1.0f / 49.0f;

    float sx[4] = {0,0,0,0}, sy[4] = {0,0,0,0}, sxx[4] = {0,0,0,0},
          syy[4] = {0,0,0,0}, sxy[4] = {0,0,0,0};
    float rgx[6][4], rgy[6][4];    // ring of raw (x,y) rows t-3..t+2

    #pragma unroll
    for (int w = 0; w < 6; ++w) {
        const int rr = t0 - 3 + w;
        float4 xv = *(const float4*)(X + (size_t)rr * F_STRIDE);
        float4 yv = *(const float4*)(Y + (size_t)rr * F_STRIDE);
        float xa[4] = {xv.x, xv.y, xv.z, xv.w}, ya[4] = {yv.x, yv.y, yv.z, yv.w};
        #pragma unroll
        for (int c = 0; c < 4; ++c) {
            sx[c] += xa[c]; sy[c] += ya[c];
            sxx[c] += xa[c]*xa[c]; syy[c] += ya[c]*ya[c]; sxy[c] += xa[c]*ya[c];
            rgx[w][c] = xa[c]; rgy[w][c] = ya[c];
        }
    }

    float4 cxa = *(const float4*)(X + (size_t)(t0 + 3) * F_STRIDE);
    float4 cya = *(const float4*)(Y + (size_t)(t0 + 3) * F_STRIDE);

    double acc = 0.0;

    #pragma unroll 1
    for (int tb = t0; tb < t1; tb += 6) {
        #pragma unroll
        for (int j = 0; j < 6; ++j) {
            const int t = tb + j;
            const int tn = min(t + 4, T_FRAMES - 1);
            float4 nxa = *(const float4*)(X + (size_t)tn * F_STRIDE);
            float4 nya = *(const float4*)(Y + (size_t)tn * F_STRIDE);

            float xa[4] = {cxa.x, cxa.y, cxa.z, cxa.w};
            float ya[4] = {cya.x, cya.y, cya.z, cya.w};

            #pragma unroll
            for (int c = 0; c < 4; ++c) {
                sx[c] += xa[c]; sy[c] += ya[c];
                sxx[c] += xa[c]*xa[c]; syy[c] += ya[c]*ya[c]; sxy[c] += xa[c]*ya[c];
            }

            float wx[4], wy[4], wxx[4], wyy[4], wxy[4];
            HWIN7(sx,  wx);
            HWIN7(sy,  wy);
            HWIN7(sxx, wxx);
            HWIN7(syy, wyy);
            HWIN7(sxy, wxy);

            const bool live = (t < t1);
            #pragma unroll
            for (int c = 0; c < 4; ++c) {
                if (live && lane_ok && (fo + c <= 1021)) {
                    float ux  = wx[c]  * inv49, uy  = wy[c]  * inv49;
                    float uxx = wxx[c] * inv49, uyy = wyy[c] * inv49, uxy = wxy[c] * inv49;
                    float vx  = COV_NORM_ * (uxx - ux * ux);
                    float vy  = COV_NORM_ * (uyy - uy * uy);
                    float vxy = COV_NORM_ * (uxy - ux * uy);
                    float num = (2.f * ux * uy + C1_) * (2.f * vxy + C2_);
                    float den = (ux * ux + uy * uy + C1_) * (vx + vy + C2_);
                    acc += (double)(num * __builtin_amdgcn_rcpf(den));
                }
            }

            #pragma unroll
            for (int c = 0; c < 4; ++c) {
                float bx_ = rgx[j][c], by_ = rgy[j][c];
                sx[c]  -= bx_;      sy[c]  -= by_;
                sxx[c] -= bx_*bx_;  syy[c] -= by_*by_;  sxy[c] -= bx_*by_;
                rgx[j][c] = xa[c];  rgy[j][c] = ya[c];
            }

            cxa = nxa; cya = nya;
        }
    }

    #pragma unroll
    for (int off = 32; off > 0; off >>= 1) acc += __shfl_down(acc, off, 64);
    if (lane == 0) {
        atomicAdd(&out[ch0 + cg], (float)(acc / (395.0 * 1019.0)));
    }
}

extern "C" void kernel_launch(void* const* d_in, const int* in_sizes, int n_in,
                              void* d_out, int out_size, void* d_ws, size_t ws_size,
                              hipStream_t stream) {
    const float* x0 = (const float*)d_in[0];   // output
    const float* x1 = (const float*)d_in[1];   // target
    float* out = (float*)d_out;
    float* ws  = (float*)d_ws;

    const size_t table_bytes  = (size_t)SPEC_OFF * sizeof(float);
    const size_t per_ch_bytes = (size_t)2 * T_FRAMES * F_STRIDE * sizeof(float);
    int G = (int)((ws_size - table_bytes) / per_ch_bytes);
    if (G > N_CH) G = N_CH;
    if (G < 1)    G = 1;

    init_tables_kernel<<<dim3(16), dim3(256), 0, stream>>>(ws, out);

    if (G >= N_CH) {
        // single swizzled 64-channel stft + single ssim (3 dispatches total)
        stft_mag_kernel<<<dim3(T_FRAMES * 64), dim3(256), 0, stream>>>(x0, x1, ws, 0, 0, N_CH, 1);
        const int nwaves = N_CH * BANDS * NCHUNKS_R;
        ssim_kernel<<<dim3((nwaves + 3) / 4), dim3(256), 0, stream>>>(ws, out, 0, N_CH);
    } else {
        for (int ch0 = 0; ch0 < N_CH; ch0 += G) {
            const int nch = (N_CH - ch0 < G) ? (N_CH - ch0) : G;
            stft_mag_kernel<<<dim3(T_FRAMES, nch), dim3(256), 0, stream>>>(x0, x1, ws, ch0, ch0, nch, 0);
            const int nwaves = nch * BANDS * NCHUNKS_R;
            ssim_kernel<<<dim3((nwaves + 3) / 4), dim3(256), 0, stream>>>(ws, out, ch0, nch);
        }
    }
}

// Round 9
// 364.526 us; speedup vs baseline: 1.0283x; 1.0283x over previous
//
#include <hip/hip_runtime.h>
#include <math.h>

#ifndef M_PI
#define M_PI 3.14159265358979323846
#endif

constexpr int S_LEN    = 176400;
constexpr int NFFT     = 2048;
constexpr int NC       = 1024;
constexpr int HOP_     = 441;
constexpr int T_FRAMES = 401;
constexpr int F_BINS   = 1025;
constexpr int F_STRIDE = 1028;     // fp32 spec row stride (16B aligned)
constexpr int N_CH     = 64;
constexpr float EPS_   = 1e-8f;
constexpr float C1_    = 0.0004f;
constexpr float C2_    = 0.0036f;
constexpr float COV_NORM_ = 49.0f / 48.0f;

// workspace float offsets
constexpr int WIN_OFF  = 0;        // float[2048] hann window
constexpr int TWG_OFF  = 2048;     // float2[768]  tw[e] = exp(-2pi i e/1024)
constexpr int UTW_OFF  = 3584;     // float2[1025] exp(-i pi r/1024)
constexpr int SPEC_OFF = 5696;

// ssim wave decomposition (R9): 9 bands x 2 cols/lane x 24-row chunks.
// R8 post-mortem: vertical chunk-halving doubled the row halo (19/12 vs 31/24)
// -> traffic-bound regression.  Horizontal split is near-free: band halo is
// 6 cols of 122, and 9x122 wastes fewer cols than 5x248.  Waves 5440->9792
// fixes R7's measured wave starvation (occ 26%, VALU 47%, BW 21%).
// Band/lane/guard geometry + HWIN2 algebra validated end-to-end in R6.
constexpr int ROWS_PW   = 24;
constexpr int NCHUNKS_R = 17;      // ceil(395/24)
constexpr int BANDS     = 9;
constexpr int BAND_ADV  = 122;     // 61 producing lanes * 2 cols

// native 2xf32 vector type -> VGPR pair, usable as inline-asm operand
typedef float vf2 __attribute__((ext_vector_type(2)));

// LDS bank swizzle: phys(i) = i ^ ((i>>2)&15) ^ ((i>>6)&15) (bijective,
// conflict-checked per access pattern in R2).
__device__ __forceinline__ int phys(int i) { return i ^ ((i >> 2) & 15) ^ ((i >> 6) & 15); }

// ---- packed-f32 complex primitives (VOP3P), absmax-verified R7/R8.
__device__ __forceinline__ vf2 pk_add(vf2 a, vf2 b) {
    vf2 r; asm("v_pk_add_f32 %0, %1, %2" : "=v"(r) : "v"(a), "v"(b)); return r;
}
__device__ __forceinline__ vf2 pk_sub(vf2 a, vf2 b) {
    vf2 r; asm("v_pk_add_f32 %0, %1, %2 neg_lo:[0,1] neg_hi:[0,1]" : "=v"(r) : "v"(a), "v"(b)); return r;
}
// {b.x + d.y, b.y - d.x}  == b - i*d
__device__ __forceinline__ vf2 pk_sub_i(vf2 b, vf2 d) {
    vf2 r; asm("v_pk_add_f32 %0, %1, %2 op_sel:[0,1] op_sel_hi:[1,0] neg_hi:[0,1]"
               : "=v"(r) : "v"(b), "v"(d)); return r;
}
// {b.x - d.y, b.y + d.x}  == b + i*d
__device__ __forceinline__ vf2 pk_add_i(vf2 b, vf2 d) {
    vf2 r; asm("v_pk_add_f32 %0, %1, %2 op_sel:[0,1] op_sel_hi:[1,0] neg_lo:[0,1]"
               : "=v"(r) : "v"(b), "v"(d)); return r;
}
// complex multiply y*w
__device__ __forceinline__ vf2 pk_cmul(vf2 y, vf2 w) {
    vf2 t, r;
    asm("v_pk_mul_f32 %0, %1, %2 op_sel:[0,0] op_sel_hi:[0,1]"
        : "=v"(t) : "v"(y), "v"(w));
    asm("v_pk_fma_f32 %0, %1, %2, %3 op_sel:[1,1,0] op_sel_hi:[1,0,1] neg_lo:[1,0,0]"
        : "=v"(r) : "v"(y), "v"(w), "v"(t));
    return r;
}

__global__ __launch_bounds__(256) void init_tables_kernel(float* __restrict__ ws, float* __restrict__ out) {
    const int idx = blockIdx.x * 256 + threadIdx.x;
    if (idx < 64) out[idx] = 0.0f;
    if (idx < NFFT) {
        ws[WIN_OFF + idx] = 0.5f - 0.5f * cosf((float)(2.0 * M_PI / NFFT) * (float)idx);
    }
    if (idx < 768) {
        float ang = -2.0f * (float)M_PI * (float)idx / (float)NC;
        float s, c; sincosf(ang, &s, &c);
        ws[TWG_OFF + 2*idx] = c; ws[TWG_OFF + 2*idx+1] = s;
    }
    if (idx < F_BINS) {
        float ang = -(float)M_PI * (float)idx / (float)NC;
        float s, c; sincosf(ang, &s, &c);
        ws[UTW_OFF + 2*idx] = c; ws[UTW_OFF + 2*idx+1] = s;
    }
}

// In-place radix-4 DIF butterfly, packed-f32 (semantics identical to R2-R5)
__device__ __forceinline__ void r4_dif_inplace(
    vf2* __restrict__ A, int r0, int r1, int r2, int r3,
    vf2 w1, vf2 w2, vf2 w3, bool tw)
{
    vf2 x0c = A[r0];
    vf2 x1c = A[r1];
    vf2 x2c = A[r2];
    vf2 x3c = A[r3];

    vf2 a = pk_add(x0c, x2c);
    vf2 b = pk_sub(x0c, x2c);
    vf2 c = pk_add(x1c, x3c);
    vf2 d = pk_sub(x1c, x3c);

    vf2 y0 = pk_add(a, c);
    vf2 y2 = pk_sub(a, c);
    vf2 y1 = pk_sub_i(b, d);
    vf2 y3 = pk_add_i(b, d);

    A[r0] = y0;
    A[r1] = tw ? pk_cmul(y1, w1) : y1;
    A[r2] = tw ? pk_cmul(y2, w2) : y2;
    A[r3] = tw ? pk_cmul(y3, w3) : y3;
}

// Dual 1024-pt in-place radix-4 DIF; one block = frame t of channel ch, both
// tensors.  16 KB LDS -> 8 blocks/CU.  Single swizzled 64-ch dispatch
// (~190us pinned across all R2-R8 variants).
__global__ __launch_bounds__(256, 8) void stft_mag_kernel(
    const float* __restrict__ x0, const float* __restrict__ x1,
    float* __restrict__ ws, int ch0, int chbase, int nlay, int swizzle)
{
    __shared__ vf2 buf[2 * NC];   // FFT0 at [0,NC), FFT1 at [NC,2NC)

    const int tid = threadIdx.x;

    int ch, t;
    if (swizzle) {
        int g = blockIdx.x;
        ch = ch0 + (g & 7) * 8 + ((g >> 3) & 7);
        t  = g >> 6;
    } else {
        t  = blockIdx.x;
        ch = ch0 + blockIdx.y;
    }

    const float* __restrict__ xin0 = x0 + (size_t)ch * S_LEN;
    const float* __restrict__ xin1 = x1 + (size_t)ch * S_LEN;
    const float* __restrict__ win  = ws + WIN_OFF;
    const vf2*   __restrict__ twg  = (const vf2*)(ws + TWG_OFF);
    const vf2*   __restrict__ utw  = (const vf2*)(ws + UTW_OFF);

    // ---- pack: flat float index n over [0,2048); complex ci = n>>1 (swizzled)
    const int base = t * HOP_ - NFFT / 2;
    float* fA0 = (float*)buf;             // FFT0
    float* fA1 = (float*)(buf + NC);      // FFT1 (+8 KB)
    if (base >= 0 && base + NFFT <= S_LEN) {
        #pragma unroll
        for (int k = 0; k < NFFT / 256; ++k) {
            int n = k * 256 + tid;
            int j = base + n;
            float w = win[n];
            int p = 2 * phys(n >> 1) + (n & 1);
            fA0[p] = xin0[j] * w;
            fA1[p] = xin1[j] * w;
        }
    } else {
        #pragma unroll
        for (int k = 0; k < NFFT / 256; ++k) {
            int n = k * 256 + tid;
            int j = base + n;
            j = (j < 0) ? -j : j;
            j = (j >= S_LEN) ? (2 * S_LEN - 2 - j) : j;
            float w = win[n];
            int p = 2 * phys(n >> 1) + (n & 1);
            fA0[p] = xin0[j] * w;
            fA1[p] = xin1[j] * w;
        }
    }
    __syncthreads();

    // ---- 5-stage in-place radix-4 DIF, x2 FFTs
    #pragma unroll
    for (int s = 0; s < 5; ++s) {
        const int M  = 256 >> (2 * s);
        const int q  = tid & (M - 1);
        const int e  = q << (2 * s);
        const int i0 = 4 * (tid - q) + q;

        const int r0 = phys(i0);
        const int r1 = phys(i0 + M);
        const int r2 = phys(i0 + 2 * M);
        const int r3 = phys(i0 + 3 * M);

        vf2 w1, w2, w3;
        if (s < 4) {
            w1 = twg[e];
            w2 = twg[2 * e];
            w3 = twg[3 * e];
        } else {
            w1.x = 1.0f; w1.y = 0.0f; w2 = w1; w3 = w1;
        }

        r4_dif_inplace(buf,      r0, r1, r2, r3, w1, w2, w3, s < 4);
        r4_dif_inplace(buf + NC, r0, r1, r2, r3, w1, w2, w3, s < 4);

        __syncthreads();
    }

    // ---- real-FFT unpack + magnitude + fp32 coalesced stores (both tensors)
    const size_t perT = (size_t)T_FRAMES * F_STRIDE;
    float* __restrict__ sout0 =
        ws + SPEC_OFF + (size_t)(ch - chbase) * perT + (size_t)t * F_STRIDE;
    float* __restrict__ sout1 = sout0 + (size_t)nlay * perT;

    const int R8 = ((tid & 3) << 6) | ((tid & 12) << 2) | ((tid >> 2) & 12) | ((tid >> 6) & 3);

    #pragma unroll
    for (int k = 0; k < 5; ++k) {
        int r = k * 256 + tid;
        if (k < 4 || tid == 0) {
            const int ra = (k < 4) ? ((R8 << 2) | k) : 0;          // rev4(r & 1023)
            const int rn = (NC - r) & (NC - 1);
            const int rb = ((rn & 3) << 8) | ((rn & 12) << 4) | (rn & 48)
                         | ((rn >> 4) & 12) | ((rn >> 8) & 3);     // rev4(rn)
            const int ia = phys(ra);
            const int ib = phys(rb);
            vf2 wu = utw[r];

            {   // tensor 0
                vf2 Zr = buf[ia];
                vf2 Zn = buf[ib];
                float Ex = 0.5f * (Zr.x + Zn.x);
                float Ey = 0.5f * (Zr.y - Zn.y);
                float Ox = 0.5f * (Zr.y + Zn.y);
                float Oy = 0.5f * (Zn.x - Zr.x);
                float Xx = Ex + wu.x * Ox - wu.y * Oy;
                float Xy = Ey + wu.x * Oy + wu.y * Ox;
                sout0[r] = sqrtf(fmaxf(Xx * Xx + Xy * Xy, EPS_));
            }
            {   // tensor 1
                vf2 Zr = buf[NC + ia];
                vf2 Zn = buf[NC + ib];
                float Ex = 0.5f * (Zr.x + Zn.x);
                float Ey = 0.5f * (Zr.y - Zn.y);
                float Ox = 0.5f * (Zr.y + Zn.y);
                float Oy = 0.5f * (Zn.x - Zr.x);
                float Xx = Ex + wu.x * Ox - wu.y * Oy;
                float Xy = Ey + wu.x * Oy + wu.y * Ox;
                sout1[r] = sqrtf(fmaxf(Xx * Xx + Xy * Xy, EPS_));
            }
        }
    }
}

// SSIM v5: 2 cols/lane, 9 bands, 24-row chunks; 6-row float2 register ring
// (read-once); horizontal 7-window from lane pair-prefixes + __shfl_down
// (HWIN2 algebra validated in R6); 1-ahead prefetch; rcp division (validated
// R8, absmax unchanged).  No LDS, no barriers.
#define HWIN2(s, W0, W1) {                                                   \
    float P  = (s).x + (s).y;                                                \
    float P1 = __shfl_down(P, 1, 64);                                        \
    float P2 = __shfl_down(P, 2, 64);                                        \
    float P3 = __shfl_down(P, 3, 64);                                        \
    float q3 = __shfl_down((s).x, 3, 64);                                    \
    float Q  = P1 + P2;                                                      \
    W0 = P + Q + q3;                                                         \
    W1 = P - (s).x + Q + P3;                                                 \
}

__global__ __launch_bounds__(256) void ssim_kernel(
    const float* __restrict__ ws, float* __restrict__ out,
    int ch0, int nch)
{
    const int tid  = threadIdx.x;
    const int wid  = blockIdx.x * 4 + (tid >> 6);
    const int lane = tid & 63;
    const int total = nch * BANDS * NCHUNKS_R;
    if (wid >= total) return;

    const int cg    = wid / (BANDS * NCHUNKS_R);
    const int rem   = wid - cg * (BANDS * NCHUNKS_R);
    const int band  = rem / NCHUNKS_R;
    const int chunk = rem - band * NCHUNKS_R;

    const int t0 = 3 + chunk * ROWS_PW;
    const int t1 = min(t0 + ROWS_PW, T_FRAMES - 3);   // <= 398

    const int cb = band * BAND_ADV;
    int c2 = cb + 2 * lane;
    if (c2 > 1026) c2 = 1026;      // in-row clamp (float2 max index 1027);
                                   // clamped lanes feed only guarded outputs

    const size_t perT = (size_t)T_FRAMES * F_STRIDE;
    const float* __restrict__ X = ws + SPEC_OFF + (size_t)cg * perT + c2;
    const float* __restrict__ Y = ws + SPEC_OFF + ((size_t)nch + cg) * perT + c2;

    const int  fo = cb + 3 + 2 * lane;   // first output col of this lane
    const bool ok = (lane <= 60);
    const float inv49 = 1.0f / 49.0f;

    float2 sx = {0,0}, sy = {0,0}, sxx = {0,0}, syy = {0,0}, sxy = {0,0};
    float2 rgx[6], rgy[6];         // ring of raw (x,y) rows t-3..t+2

    #pragma unroll
    for (int w = 0; w < 6; ++w) {
        const int rr = t0 - 3 + w;
        float2 xv = *(const float2*)(X + (size_t)rr * F_STRIDE);
        float2 yv = *(const float2*)(Y + (size_t)rr * F_STRIDE);
        sx.x += xv.x; sx.y += xv.y; sy.x += yv.x; sy.y += yv.y;
        sxx.x += xv.x*xv.x; sxx.y += xv.y*xv.y;
        syy.x += yv.x*yv.x; syy.y += yv.y*yv.y;
        sxy.x += xv.x*yv.x; sxy.y += xv.y*yv.y;
        rgx[w] = xv; rgy[w] = yv;
    }

    float2 cxa = *(const float2*)(X + (size_t)(t0 + 3) * F_STRIDE);
    float2 cya = *(const float2*)(Y + (size_t)(t0 + 3) * F_STRIDE);

    double acc = 0.0;

    #pragma unroll 1
    for (int tb = t0; tb < t1; tb += 6) {
        #pragma unroll
        for (int j = 0; j < 6; ++j) {
            const int t = tb + j;
            const int tn = min(t + 4, T_FRAMES - 1);
            float2 nxa = *(const float2*)(X + (size_t)tn * F_STRIDE);
            float2 nya = *(const float2*)(Y + (size_t)tn * F_STRIDE);

            // add row t+3 (prefetched)
            sx.x += cxa.x; sx.y += cxa.y; sy.x += cya.x; sy.y += cya.y;
            sxx.x += cxa.x*cxa.x; sxx.y += cxa.y*cxa.y;
            syy.x += cya.x*cya.x; syy.y += cya.y*cya.y;
            sxy.x += cxa.x*cya.x; sxy.y += cxa.y*cya.y;

            float wx0,wx1, wy0,wy1, wxx0,wxx1, wyy0,wyy1, wxy0,wxy1;
            HWIN2(sx,  wx0,  wx1);
            HWIN2(sy,  wy0,  wy1);
            HWIN2(sxx, wxx0, wxx1);
            HWIN2(syy, wyy0, wyy1);
            HWIN2(sxy, wxy0, wxy1);

            const bool live = (t < t1);
            if (live && ok && fo <= 1021) {
                float ux  = wx0 * inv49, uy  = wy0 * inv49;
                float uxx = wxx0 * inv49, uyy = wyy0 * inv49, uxy = wxy0 * inv49;
                float vx  = COV_NORM_ * (uxx - ux * ux);
                float vy  = COV_NORM_ * (uyy - uy * uy);
                float vxy = COV_NORM_ * (uxy - ux * uy);
                float num = (2.f * ux * uy + C1_) * (2.f * vxy + C2_);
                float den = (ux * ux + uy * uy + C1_) * (vx + vy + C2_);
                acc += (double)(num * __builtin_amdgcn_rcpf(den));
            }
            if (live && ok && fo + 1 <= 1021) {
                float ux  = wx1 * inv49, uy  = wy1 * inv49;
                float uxx = wxx1 * inv49, uyy = wyy1 * inv49, uxy = wxy1 * inv49;
                float vx  = COV_NORM_ * (uxx - ux * ux);
                float vy  = COV_NORM_ * (uyy - uy * uy);
                float vxy = COV_NORM_ * (uxy - ux * uy);
                float num = (2.f * ux * uy + C1_) * (2.f * vxy + C2_);
                float den = (ux * ux + uy * uy + C1_) * (vx + vy + C2_);
                acc += (double)(num * __builtin_amdgcn_rcpf(den));
            }

            // subtract row t-3 from the ring (static slot j), store new row
            {
                float2 bx_ = rgx[j], by_ = rgy[j];
                sx.x  -= bx_.x;      sx.y  -= bx_.y;
                sy.x  -= by_.x;      sy.y  -= by_.y;
                sxx.x -= bx_.x*bx_.x; sxx.y -= bx_.y*bx_.y;
                syy.x -= by_.x*by_.x; syy.y -= by_.y*by_.y;
                sxy.x -= bx_.x*by_.x; sxy.y -= bx_.y*by_.y;
                rgx[j] = cxa; rgy[j] = cya;
            }

            cxa = nxa; cya = nya;
        }
    }

    #pragma unroll
    for (int off = 32; off > 0; off >>= 1) acc += __shfl_down(acc, off, 64);
    if (lane == 0) {
        atomicAdd(&out[ch0 + cg], (float)(acc / (395.0 * 1019.0)));
    }
}

extern "C" void kernel_launch(void* const* d_in, const int* in_sizes, int n_in,
                              void* d_out, int out_size, void* d_ws, size_t ws_size,
                              hipStream_t stream) {
    const float* x0 = (const float*)d_in[0];   // output
    const float* x1 = (const float*)d_in[1];   // target
    float* out = (float*)d_out;
    float* ws  = (float*)d_ws;

    const size_t table_bytes  = (size_t)SPEC_OFF * sizeof(float);
    const size_t per_ch_bytes = (size_t)2 * T_FRAMES * F_STRIDE * sizeof(float);
    int G = (int)((ws_size - table_bytes) / per_ch_bytes);
    if (G > N_CH) G = N_CH;
    if (G < 1)    G = 1;

    init_tables_kernel<<<dim3(16), dim3(256), 0, stream>>>(ws, out);

    if (G >= N_CH) {
        // single swizzled 64-channel stft + single ssim (3 dispatches total)
        stft_mag_kernel<<<dim3(T_FRAMES * 64), dim3(256), 0, stream>>>(x0, x1, ws, 0, 0, N_CH, 1);
        const int nwaves = N_CH * BANDS * NCHUNKS_R;
        ssim_kernel<<<dim3((nwaves + 3) / 4), dim3(256), 0, stream>>>(ws, out, 0, N_CH);
    } else {
        for (int ch0 = 0; ch0 < N_CH; ch0 += G) {
            const int nch = (N_CH - ch0 < G) ? (N_CH - ch0) : G;
            stft_mag_kernel<<<dim3(T_FRAMES, nch), dim3(256), 0, stream>>>(x0, x1, ws, ch0, ch0, nch, 0);
            const int nwaves = nch * BANDS * NCHUNKS_R;
            ssim_kernel<<<dim3((nwaves + 3) / 4), dim3(256), 0, stream>>>(ws, out, ch0, nch);
        }
    }
}

// Round 11
// 329.445 us; speedup vs baseline: 1.1378x; 1.1065x over previous
//
#include <hip/hip_runtime.h>
#include <math.h>

#ifndef M_PI
#define M_PI 3.14159265358979323846
#endif

constexpr int S_LEN    = 176400;
constexpr int NFFT     = 2048;
constexpr int NC       = 1024;
constexpr int HOP_     = 441;
constexpr int T_FRAMES = 401;
constexpr int F_BINS   = 1025;
constexpr int F_STRIDE = 1028;     // fp32 spec row stride (16B aligned)
constexpr int N_CH     = 64;
constexpr float EPS_   = 1e-8f;
constexpr float C1_    = 0.0004f;
constexpr float C2_    = 0.0036f;
constexpr float COV_NORM_ = 49.0f / 48.0f;

// workspace float offsets
constexpr int WIN_OFF  = 0;        // float[2048] hann window
constexpr int TWG_OFF  = 2048;     // float2[768]  tw[e] = exp(-2pi i e/1024)
constexpr int UTW_OFF  = 3584;     // float2[1025] exp(-i pi r/1024)
constexpr int SPEC_OFF = 5696;

// ssim wave decomposition: REVERTED to proven-best R5 geometry
// (4 cols/lane x 5 bands x 24-row chunks; R8 vertical and R9 horizontal
// splits both regressed).  R10 change is the 4-stat fusion below.
constexpr int ROWS_PW   = 24;
constexpr int NCHUNKS_R = 17;      // ceil(395/24)
constexpr int BANDS     = 5;
constexpr int BAND_ADV  = 248;     // 62 producing lanes * 4 cols

// native 2xf32 vector type -> VGPR pair, usable as inline-asm operand
typedef float vf2 __attribute__((ext_vector_type(2)));

// LDS bank swizzle: phys(i) = i ^ ((i>>2)&15) ^ ((i>>6)&15) (bijective,
// conflict-checked per access pattern in R2).
__device__ __forceinline__ int phys(int i) { return i ^ ((i >> 2) & 15) ^ ((i >> 6) & 15); }

// ---- packed-f32 complex primitives (VOP3P), absmax-verified R7-R9.
__device__ __forceinline__ vf2 pk_add(vf2 a, vf2 b) {
    vf2 r; asm("v_pk_add_f32 %0, %1, %2" : "=v"(r) : "v"(a), "v"(b)); return r;
}
__device__ __forceinline__ vf2 pk_sub(vf2 a, vf2 b) {
    vf2 r; asm("v_pk_add_f32 %0, %1, %2 neg_lo:[0,1] neg_hi:[0,1]" : "=v"(r) : "v"(a), "v"(b)); return r;
}
// {b.x + d.y, b.y - d.x}  == b - i*d
__device__ __forceinline__ vf2 pk_sub_i(vf2 b, vf2 d) {
    vf2 r; asm("v_pk_add_f32 %0, %1, %2 op_sel:[0,1] op_sel_hi:[1,0] neg_hi:[0,1]"
               : "=v"(r) : "v"(b), "v"(d)); return r;
}
// {b.x - d.y, b.y + d.x}  == b + i*d
__device__ __forceinline__ vf2 pk_add_i(vf2 b, vf2 d) {
    vf2 r; asm("v_pk_add_f32 %0, %1, %2 op_sel:[0,1] op_sel_hi:[1,0] neg_lo:[0,1]"
               : "=v"(r) : "v"(b), "v"(d)); return r;
}
// complex multiply y*w
__device__ __forceinline__ vf2 pk_cmul(vf2 y, vf2 w) {
    vf2 t, r;
    asm("v_pk_mul_f32 %0, %1, %2 op_sel:[0,0] op_sel_hi:[0,1]"
        : "=v"(t) : "v"(y), "v"(w));
    asm("v_pk_fma_f32 %0, %1, %2, %3 op_sel:[1,1,0] op_sel_hi:[1,0,1] neg_lo:[1,0,0]"
        : "=v"(r) : "v"(y), "v"(w), "v"(t));
    return r;
}

__global__ __launch_bounds__(256) void init_tables_kernel(float* __restrict__ ws, float* __restrict__ out) {
    const int idx = blockIdx.x * 256 + threadIdx.x;
    if (idx < 64) out[idx] = 0.0f;
    if (idx < NFFT) {
        ws[WIN_OFF + idx] = 0.5f - 0.5f * cosf((float)(2.0 * M_PI / NFFT) * (float)idx);
    }
    if (idx < 768) {
        float ang = -2.0f * (float)M_PI * (float)idx / (float)NC;
        float s, c; sincosf(ang, &s, &c);
        ws[TWG_OFF + 2*idx] = c; ws[TWG_OFF + 2*idx+1] = s;
    }
    if (idx < F_BINS) {
        float ang = -(float)M_PI * (float)idx / (float)NC;
        float s, c; sincosf(ang, &s, &c);
        ws[UTW_OFF + 2*idx] = c; ws[UTW_OFF + 2*idx+1] = s;
    }
}

// In-place radix-4 DIF butterfly, packed-f32 (semantics identical to R2-R5)
__device__ __forceinline__ void r4_dif_inplace(
    vf2* __restrict__ A, int r0, int r1, int r2, int r3,
    vf2 w1, vf2 w2, vf2 w3, bool tw)
{
    vf2 x0c = A[r0];
    vf2 x1c = A[r1];
    vf2 x2c = A[r2];
    vf2 x3c = A[r3];

    vf2 a = pk_add(x0c, x2c);
    vf2 b = pk_sub(x0c, x2c);
    vf2 c = pk_add(x1c, x3c);
    vf2 d = pk_sub(x1c, x3c);

    vf2 y0 = pk_add(a, c);
    vf2 y2 = pk_sub(a, c);
    vf2 y1 = pk_sub_i(b, d);
    vf2 y3 = pk_add_i(b, d);

    A[r0] = y0;
    A[r1] = tw ? pk_cmul(y1, w1) : y1;
    A[r2] = tw ? pk_cmul(y2, w2) : y2;
    A[r3] = tw ? pk_cmul(y3, w3) : y3;
}

// Dual 1024-pt in-place radix-4 DIF; one block = frame t of channel ch, both
// tensors.  16 KB LDS -> 8 blocks/CU.  Single swizzled 64-ch dispatch
// (~190us pinned across all R2-R9 variants).
__global__ __launch_bounds__(256, 8) void stft_mag_kernel(
    const float* __restrict__ x0, const float* __restrict__ x1,
    float* __restrict__ ws, int ch0, int chbase, int nlay, int swizzle)
{
    __shared__ vf2 buf[2 * NC];   // FFT0 at [0,NC), FFT1 at [NC,2NC)

    const int tid = threadIdx.x;

    int ch, t;
    if (swizzle) {
        int g = blockIdx.x;
        ch = ch0 + (g & 7) * 8 + ((g >> 3) & 7);
        t  = g >> 6;
    } else {
        t  = blockIdx.x;
        ch = ch0 + blockIdx.y;
    }

    const float* __restrict__ xin0 = x0 + (size_t)ch * S_LEN;
    const float* __restrict__ xin1 = x1 + (size_t)ch * S_LEN;
    const float* __restrict__ win  = ws + WIN_OFF;
    const vf2*   __restrict__ twg  = (const vf2*)(ws + TWG_OFF);
    const vf2*   __restrict__ utw  = (const vf2*)(ws + UTW_OFF);

    // ---- pack: flat float index n over [0,2048); complex ci = n>>1 (swizzled)
    const int base = t * HOP_ - NFFT / 2;
    float* fA0 = (float*)buf;             // FFT0
    float* fA1 = (float*)(buf + NC);      // FFT1 (+8 KB)
    if (base >= 0 && base + NFFT <= S_LEN) {
        #pragma unroll
        for (int k = 0; k < NFFT / 256; ++k) {
            int n = k * 256 + tid;
            int j = base + n;
            float w = win[n];
            int p = 2 * phys(n >> 1) + (n & 1);
            fA0[p] = xin0[j] * w;
            fA1[p] = xin1[j] * w;
        }
    } else {
        #pragma unroll
        for (int k = 0; k < NFFT / 256; ++k) {
            int n = k * 256 + tid;
            int j = base + n;
            j = (j < 0) ? -j : j;
            j = (j >= S_LEN) ? (2 * S_LEN - 2 - j) : j;
            float w = win[n];
            int p = 2 * phys(n >> 1) + (n & 1);
            fA0[p] = xin0[j] * w;
            fA1[p] = xin1[j] * w;
        }
    }
    __syncthreads();

    // ---- 5-stage in-place radix-4 DIF, x2 FFTs
    #pragma unroll
    for (int s = 0; s < 5; ++s) {
        const int M  = 256 >> (2 * s);
        const int q  = tid & (M - 1);
        const int e  = q << (2 * s);
        const int i0 = 4 * (tid - q) + q;

        const int r0 = phys(i0);
        const int r1 = phys(i0 + M);
        const int r2 = phys(i0 + 2 * M);
        const int r3 = phys(i0 + 3 * M);

        vf2 w1, w2, w3;
        if (s < 4) {
            w1 = twg[e];
            w2 = twg[2 * e];
            w3 = twg[3 * e];
        } else {
            w1.x = 1.0f; w1.y = 0.0f; w2 = w1; w3 = w1;
        }

        r4_dif_inplace(buf,      r0, r1, r2, r3, w1, w2, w3, s < 4);
        r4_dif_inplace(buf + NC, r0, r1, r2, r3, w1, w2, w3, s < 4);

        __syncthreads();
    }

    // ---- real-FFT unpack + magnitude + fp32 coalesced stores (both tensors)
    const size_t perT = (size_t)T_FRAMES * F_STRIDE;
    float* __restrict__ sout0 =
        ws + SPEC_OFF + (size_t)(ch - chbase) * perT + (size_t)t * F_STRIDE;
    float* __restrict__ sout1 = sout0 + (size_t)nlay * perT;

    const int R8 = ((tid & 3) << 6) | ((tid & 12) << 2) | ((tid >> 2) & 12) | ((tid >> 6) & 3);

    #pragma unroll
    for (int k = 0; k < 5; ++k) {
        int r = k * 256 + tid;
        if (k < 4 || tid == 0) {
            const int ra = (k < 4) ? ((R8 << 2) | k) : 0;          // rev4(r & 1023)
            const int rn = (NC - r) & (NC - 1);
            const int rb = ((rn & 3) << 8) | ((rn & 12) << 4) | (rn & 48)
                         | ((rn >> 4) & 12) | ((rn >> 8) & 3);     // rev4(rn)
            const int ia = phys(ra);
            const int ib = phys(rb);
            vf2 wu = utw[r];

            {   // tensor 0
                vf2 Zr = buf[ia];
                vf2 Zn = buf[ib];
                float Ex = 0.5f * (Zr.x + Zn.x);
                float Ey = 0.5f * (Zr.y - Zn.y);
                float Ox = 0.5f * (Zr.y + Zn.y);
                float Oy = 0.5f * (Zn.x - Zr.x);
                float Xx = Ex + wu.x * Ox - wu.y * Oy;
                float Xy = Ey + wu.x * Oy + wu.y * Ox;
                sout0[r] = sqrtf(fmaxf(Xx * Xx + Xy * Xy, EPS_));
            }
            {   // tensor 1
                vf2 Zr = buf[NC + ia];
                vf2 Zn = buf[NC + ib];
                float Ex = 0.5f * (Zr.x + Zn.x);
                float Ey = 0.5f * (Zr.y - Zn.y);
                float Ox = 0.5f * (Zr.y + Zn.y);
                float Oy = 0.5f * (Zn.x - Zr.x);
                float Xx = Ex + wu.x * Ox - wu.y * Oy;
                float Xy = Ey + wu.x * Oy + wu.y * Ox;
                sout1[r] = sqrtf(fmaxf(Xx * Xx + Xy * Xy, EPS_));
            }
        }
    }
}

// SSIM v6: R5 ring structure (proven best: 4 cols/lane, 5 bands, ROWS_PW 24,
// read-once ring, 1-ahead prefetch, rcp div) with 4-STAT FUSION:
// SSIM uses vx,vy only as vx+vy = COV*((uxx+uyy) - (ux^2+uy^2)), so sxx and
// syy fuse into one windowed stat s2 = sxx+syy.  5 stats -> 4: -20% on the
// co-critical per-CU DS (shuffle) pipe (16 vs 20 shuffles/row) and fewer
// window combines, at identical geometry/traffic/occupancy.  Algebraically
// exact.
#define HWIN7(sarr, W) {                                                     \
    float p0 = sarr[0], p01 = p0 + sarr[1], p012 = p01 + sarr[2],            \
          P = p012 + sarr[3];                                                \
    float a1 = __shfl_down(p012, 1, 64);                                     \
    float A1 = __shfl_down(P,    1, 64);                                     \
    float b0 = __shfl_down(p0,   2, 64);                                     \
    float b1 = __shfl_down(p01,  2, 64);                                     \
    W[0] = P + a1;                                                           \
    W[1] = P - p0 + A1;                                                      \
    W[2] = W[1] - sarr[1] + b0;                                              \
    W[3] = W[2] - sarr[2] + (b1 - b0);                                       \
}

__global__ __launch_bounds__(256) void ssim_kernel(
    const float* __restrict__ ws, float* __restrict__ out,
    int ch0, int nch)
{
    const int tid  = threadIdx.x;
    const int wid  = blockIdx.x * 4 + (tid >> 6);
    const int lane = tid & 63;
    const int total = nch * BANDS * NCHUNKS_R;
    if (wid >= total) return;

    const int cg    = wid / (BANDS * NCHUNKS_R);
    const int rem   = wid - cg * (BANDS * NCHUNKS_R);
    const int band  = rem / NCHUNKS_R;
    const int chunk = rem - band * NCHUNKS_R;

    const int t0 = 3 + chunk * ROWS_PW;
    const int t1 = min(t0 + ROWS_PW, T_FRAMES - 3);   // <= 398

    const int cb = band * BAND_ADV;
    int c4 = cb + 4 * lane;
    if (c4 > 1024) c4 = 1024;      // stay inside the 1028-float row (no OOB)

    const size_t perT = (size_t)T_FRAMES * F_STRIDE;
    const float* __restrict__ X = ws + SPEC_OFF + (size_t)cg * perT + c4;
    const float* __restrict__ Y = ws + SPEC_OFF + ((size_t)nch + cg) * perT + c4;

    const int  fo      = cb + 3 + 4 * lane;   // first output col of this lane
    const bool lane_ok = (lane <= 61);
    const float inv49  = 1.0f / 49.0f;

    // 4 windowed stats: sx, sy, s2 = sxx+syy, sxy
    float sx[4] = {0,0,0,0}, sy[4] = {0,0,0,0}, s2[4] = {0,0,0,0},
          sxy[4] = {0,0,0,0};
    float rgx[6][4], rgy[6][4];    // ring of raw (x,y) rows t-3..t+2

    #pragma unroll
    for (int w = 0; w < 6; ++w) {
        const int rr = t0 - 3 + w;
        float4 xv = *(const float4*)(X + (size_t)rr * F_STRIDE);
        float4 yv = *(const float4*)(Y + (size_t)rr * F_STRIDE);
        float xa[4] = {xv.x, xv.y, xv.z, xv.w}, ya[4] = {yv.x, yv.y, yv.z, yv.w};
        #pragma unroll
        for (int c = 0; c < 4; ++c) {
            sx[c] += xa[c]; sy[c] += ya[c];
            s2[c] += xa[c]*xa[c] + ya[c]*ya[c];
            sxy[c] += xa[c]*ya[c];
            rgx[w][c] = xa[c]; rgy[w][c] = ya[c];
        }
    }

    float4 cxa = *(const float4*)(X + (size_t)(t0 + 3) * F_STRIDE);
    float4 cya = *(const float4*)(Y + (size_t)(t0 + 3) * F_STRIDE);

    double acc = 0.0;

    #pragma unroll 1
    for (int tb = t0; tb < t1; tb += 6) {
        #pragma unroll
        for (int j = 0; j < 6; ++j) {
            const int t = tb + j;
            const int tn = min(t + 4, T_FRAMES - 1);
            float4 nxa = *(const float4*)(X + (size_t)tn * F_STRIDE);
            float4 nya = *(const float4*)(Y + (size_t)tn * F_STRIDE);

            float xa[4] = {cxa.x, cxa.y, cxa.z, cxa.w};
            float ya[4] = {cya.x, cya.y, cya.z, cya.w};

            // add row t+3 (prefetched)
            #pragma unroll
            for (int c = 0; c < 4; ++c) {
                sx[c] += xa[c]; sy[c] += ya[c];
                s2[c] += xa[c]*xa[c] + ya[c]*ya[c];
                sxy[c] += xa[c]*ya[c];
            }

            float wx[4], wy[4], w2[4], wxy[4];
            HWIN7(sx,  wx);
            HWIN7(sy,  wy);
            HWIN7(s2,  w2);
            HWIN7(sxy, wxy);

            const bool live = (t < t1);
            #pragma unroll
            for (int c = 0; c < 4; ++c) {
                if (live && lane_ok && (fo + c <= 1021)) {
                    float ux  = wx[c]  * inv49, uy  = wy[c]  * inv49;
                    float u2  = w2[c]  * inv49, uxy = wxy[c] * inv49;
                    float upq = ux * ux + uy * uy;
                    float vs  = COV_NORM_ * (u2 - upq);        // vx + vy
                    float vxy = COV_NORM_ * (uxy - ux * uy);
                    float num = (2.f * ux * uy + C1_) * (2.f * vxy + C2_);
                    float den = (upq + C1_) * (vs + C2_);
                    acc += (double)(num * __builtin_amdgcn_rcpf(den));
                }
            }

            // subtract row t-3 from the ring (static slot j), store new row
            #pragma unroll
            for (int c = 0; c < 4; ++c) {
                float bx_ = rgx[j][c], by_ = rgy[j][c];
                sx[c]  -= bx_;      sy[c]  -= by_;
                s2[c]  -= bx_*bx_ + by_*by_;
                sxy[c] -= bx_*by_;
                rgx[j][c] = xa[c];  rgy[j][c] = ya[c];
            }

            cxa = nxa; cya = nya;
        }
    }

    #pragma unroll
    for (int off = 32; off > 0; off >>= 1) acc += __shfl_down(acc, off, 64);
    if (lane == 0) {
        atomicAdd(&out[ch0 + cg], (float)(acc / (395.0 * 1019.0)));
    }
}

extern "C" void kernel_launch(void* const* d_in, const int* in_sizes, int n_in,
                              void* d_out, int out_size, void* d_ws, size_t ws_size,
                              hipStream_t stream) {
    const float* x0 = (const float*)d_in[0];   // output
    const float* x1 = (const float*)d_in[1];   // target
    float* out = (float*)d_out;
    float* ws  = (float*)d_ws;

    const size_t table_bytes  = (size_t)SPEC_OFF * sizeof(float);
    const size_t per_ch_bytes = (size_t)2 * T_FRAMES * F_STRIDE * sizeof(float);
    int G = (int)((ws_size - table_bytes) / per_ch_bytes);
    if (G > N_CH) G = N_CH;
    if (G < 1)    G = 1;

    init_tables_kernel<<<dim3(16), dim3(256), 0, stream>>>(ws, out);

    if (G >= N_CH) {
        // single swizzled 64-channel stft + single ssim (3 dispatches total)
        stft_mag_kernel<<<dim3(T_FRAMES * 64), dim3(256), 0, stream>>>(x0, x1, ws, 0, 0, N_CH, 1);
        const int nwaves = N_CH * BANDS * NCHUNKS_R;
        ssim_kernel<<<dim3((nwaves + 3) / 4), dim3(256), 0, stream>>>(ws, out, 0, N_CH);
    } else {
        for (int ch0 = 0; ch0 < N_CH; ch0 += G) {
            const int nch = (N_CH - ch0 < G) ? (N_CH - ch0) : G;
            stft_mag_kernel<<<dim3(T_FRAMES, nch), dim3(256), 0, stream>>>(x0, x1, ws, ch0, ch0, nch, 0);
            const int nwaves = nch * BANDS * NCHUNKS_R;
            ssim_kernel<<<dim3((nwaves + 3) / 4), dim3(256), 0, stream>>>(ws, out, ch0, nch);
        }
    }
}